// Round 5
// baseline (295.415 us; speedup 1.0000x reference)
//
#include <hip/hip_runtime.h>
#include <hip/hip_bf16.h>
#include <math.h>

constexpr int B_  = 4;
constexpr int S_  = 1024;
constexpr int D_  = 512;
constexpr int H_  = 8;
constexpr int DK_ = 64;
constexpr int MROWS_ = B_ * S_;          // 4096
constexpr size_t SZ_ = (size_t)B_ * H_ * S_ * DK_;  // 2M elems per tensor
constexpr size_t WSZ_ = (size_t)D_ * D_;            // 256K elems per weight

typedef __attribute__((ext_vector_type(8))) short bf16x8;
typedef __attribute__((ext_vector_type(4))) float f32x4;

__device__ __forceinline__ float bf2f(unsigned short u) {
  union { unsigned int u; float f; } v; v.u = (unsigned int)u << 16; return v.f;
}
__device__ __forceinline__ unsigned short f2bf(float f) {
  union { float f; unsigned int u; } v; v.f = f;
  unsigned int r = v.u + 0x7FFFu + ((v.u >> 16) & 1u);   // RNE
  return (unsigned short)(r >> 16);
}

// ---- DPP cross-lane helpers (VALU pipe, no LDS) ----
template <int CTRL>
__device__ __forceinline__ float dpp_mov_f(float x) {
  return __builtin_bit_cast(float,
      __builtin_amdgcn_update_dpp(0, __builtin_bit_cast(int, x), CTRL, 0xF, 0xF, true));
}
__device__ __forceinline__ float scan16(float v) {
  v += dpp_mov_f<0x111>(v);   // row_shr:1
  v += dpp_mov_f<0x112>(v);   // row_shr:2
  v += dpp_mov_f<0x114>(v);   // row_shr:4
  v += dpp_mov_f<0x118>(v);   // row_shr:8
  return v;
}
__device__ __forceinline__ float red16(float v) {
  v += dpp_mov_f<0x128>(v);   // row_ror:8
  v += dpp_mov_f<0x124>(v);   // row_ror:4
  v += dpp_mov_f<0x122>(v);   // row_ror:2
  v += dpp_mov_f<0x121>(v);   // row_ror:1
  return v;
}
// broadcast lane15 of each 16-lane group
__device__ __forceinline__ float bcast15(float v) {
  return __builtin_bit_cast(float,
      __builtin_amdgcn_ds_swizzle(__builtin_bit_cast(int, v), 0x01F0));
}

// ---------------------------------------------------------------------------
// W transpose+convert (unchanged from R4).
// ---------------------------------------------------------------------------
struct TpArgs { const float* W[4]; unsigned short* out[4]; };

__global__ __launch_bounds__(256) void wtrans(TpArgs a) {
  const int z = blockIdx.z;
  const float* __restrict__ W = a.W[z];
  unsigned short* __restrict__ out = a.out[z];
  __shared__ float T[64][65];
  const int tid = threadIdx.x;
  const int tx = blockIdx.x & 7, ty = blockIdx.x >> 3;
  const int k0 = ty * 64, n0 = tx * 64;
#pragma unroll
  for (int i = 0; i < 4; ++i) {
    const int idx = tid + i * 256;
    const int r = idx >> 4, c4 = (idx & 15) * 4;
    const float4 w = *(const float4*)&W[(size_t)(k0 + r) * D_ + n0 + c4];
    T[r][c4 + 0] = w.x; T[r][c4 + 1] = w.y; T[r][c4 + 2] = w.z; T[r][c4 + 3] = w.w;
  }
  __syncthreads();
#pragma unroll
  for (int i = 0; i < 4; ++i) {
    const int idx = tid + i * 256;
    const int n = idx >> 4, kc = (idx & 15) * 4;
    ushort4 pk;
    pk.x = f2bf(T[kc + 0][n]); pk.y = f2bf(T[kc + 1][n]);
    pk.z = f2bf(T[kc + 2][n]); pk.w = f2bf(T[kc + 3][n]);
    *(ushort4*)&out[(size_t)(n0 + n) * D_ + k0 + kc] = pk;
  }
}

// ---------------------------------------------------------------------------
// MFMA projection GEMM (unchanged from R4).
// ---------------------------------------------------------------------------
struct ProjArgs {
  const float* A[6]; const unsigned short* Wt[6]; const float* bias[6];
  unsigned short* out[6]; int vmode[6];
};

__global__ __launch_bounds__(256) void proj_mfma(ProjArgs args) {
  const int z = blockIdx.z;
  const float* __restrict__ A = args.A[z];
  const unsigned short* __restrict__ Wt = args.Wt[z];
  const float* __restrict__ bias = args.bias[z];
  unsigned short* __restrict__ out = args.out[z];
  const int vmode = args.vmode[z];

  __shared__ unsigned short Abuf[128][40];
  __shared__ unsigned short Bbuf[128][40];
  const int tid = threadIdx.x, wv = tid >> 6, lane = tid & 63;
  const int quad = lane >> 4, l16 = lane & 15;
  const int wm = wv >> 1, wn = wv & 1;
  const int n0 = blockIdx.x * 128, m0 = blockIdx.y * 128;

  f32x4 acc[4][4];
#pragma unroll
  for (int i = 0; i < 4; ++i)
#pragma unroll
    for (int j = 0; j < 4; ++j) acc[i][j] = (f32x4){0.f, 0.f, 0.f, 0.f};

  for (int kt = 0; kt < 16; ++kt) {
    const int k0 = kt * 32;
    __syncthreads();
#pragma unroll
    for (int i = 0; i < 4; ++i) {
      const int idx = tid + i * 256;
      const int m = idx >> 3, c = idx & 7;
      const float4 av = *(const float4*)&A[(size_t)(m0 + m) * D_ + k0 + c * 4];
      ushort4 p;
      p.x = f2bf(av.x); p.y = f2bf(av.y); p.z = f2bf(av.z); p.w = f2bf(av.w);
      *(ushort4*)&Abuf[m][c * 4] = p;
    }
#pragma unroll
    for (int i = 0; i < 2; ++i) {
      const int idx = tid + i * 256;
      const int n = idx >> 2, c = idx & 3;
      *(uint4*)&Bbuf[n][c * 8] = *(const uint4*)&Wt[(size_t)(n0 + n) * D_ + k0 + c * 8];
    }
    __syncthreads();

    bf16x8 af[4], bfr[4];
#pragma unroll
    for (int i = 0; i < 4; ++i) af[i] = *(const bf16x8*)&Abuf[wm * 64 + i * 16 + l16][quad * 8];
#pragma unroll
    for (int j = 0; j < 4; ++j) bfr[j] = *(const bf16x8*)&Bbuf[wn * 64 + j * 16 + l16][quad * 8];
#pragma unroll
    for (int i = 0; i < 4; ++i)
#pragma unroll
      for (int j = 0; j < 4; ++j)
        acc[i][j] = __builtin_amdgcn_mfma_f32_16x16x32_bf16(af[i], bfr[j], acc[i][j], 0, 0, 0);
  }

#pragma unroll
  for (int j = 0; j < 4; ++j) {
    const int col = n0 + wn * 64 + j * 16 + l16;
    const float bv = bias[col];
    const int h = col >> 6, dk = col & 63;
#pragma unroll
    for (int i = 0; i < 4; ++i) {
      const int mbase = m0 + wm * 64 + i * 16 + quad * 4;
      const int b = mbase >> 10;
      if (!vmode) {
#pragma unroll
        for (int r = 0; r < 4; ++r) {
          const int s = (mbase + r) & 1023;
          out[(((size_t)b * H_ + h) * S_ + s) * DK_ + dk] = f2bf(acc[i][j][r] + bv);
        }
      } else {
        const int s = mbase & 1023;
        ushort4 pk;
        pk.x = f2bf(acc[i][j][0] + bv); pk.y = f2bf(acc[i][j][1] + bv);
        pk.z = f2bf(acc[i][j][2] + bv); pk.w = f2bf(acc[i][j][3] + bv);
        *(ushort4*)&out[(((size_t)b * H_ + h) * DK_ + dk) * S_ + s] = pk;
      }
    }
  }
}

// ---------------------------------------------------------------------------
// MFMA output GEMM (unchanged from R4).
// ---------------------------------------------------------------------------
struct OutArgs {
  const unsigned short* A[2]; const unsigned short* Wt[2];
  const float* bias[2]; float* out[2];
};

__global__ __launch_bounds__(256) void out_mfma(OutArgs args) {
  const int z = blockIdx.z;
  const unsigned short* __restrict__ A = args.A[z];
  const unsigned short* __restrict__ Wt = args.Wt[z];
  const float* __restrict__ bias = args.bias[z];
  float* __restrict__ out = args.out[z];

  __shared__ unsigned short Abuf[128][40];
  __shared__ unsigned short Bbuf[128][40];
  const int tid = threadIdx.x, wv = tid >> 6, lane = tid & 63;
  const int quad = lane >> 4, l16 = lane & 15;
  const int wm = wv >> 1, wn = wv & 1;
  const int n0 = blockIdx.x * 128, m0 = blockIdx.y * 128;

  f32x4 acc[4][4];
#pragma unroll
  for (int i = 0; i < 4; ++i)
#pragma unroll
    for (int j = 0; j < 4; ++j) acc[i][j] = (f32x4){0.f, 0.f, 0.f, 0.f};

  for (int kt = 0; kt < 16; ++kt) {
    const int k0 = kt * 32;
    __syncthreads();
#pragma unroll
    for (int i = 0; i < 2; ++i) {
      const int idx = tid + i * 256;
      const int m = idx >> 2, c = idx & 3;
      *(uint4*)&Abuf[m][c * 8] = *(const uint4*)&A[(size_t)(m0 + m) * D_ + k0 + c * 8];
    }
#pragma unroll
    for (int i = 0; i < 2; ++i) {
      const int idx = tid + i * 256;
      const int n = idx >> 2, c = idx & 3;
      *(uint4*)&Bbuf[n][c * 8] = *(const uint4*)&Wt[(size_t)(n0 + n) * D_ + k0 + c * 8];
    }
    __syncthreads();

    bf16x8 af[4], bfr[4];
#pragma unroll
    for (int i = 0; i < 4; ++i) af[i] = *(const bf16x8*)&Abuf[wm * 64 + i * 16 + l16][quad * 8];
#pragma unroll
    for (int j = 0; j < 4; ++j) bfr[j] = *(const bf16x8*)&Bbuf[wn * 64 + j * 16 + l16][quad * 8];
#pragma unroll
    for (int i = 0; i < 4; ++i)
#pragma unroll
      for (int j = 0; j < 4; ++j)
        acc[i][j] = __builtin_amdgcn_mfma_f32_16x16x32_bf16(af[i], bfr[j], acc[i][j], 0, 0, 0);
  }

#pragma unroll
  for (int j = 0; j < 4; ++j) {
    const int col = n0 + wn * 64 + j * 16 + l16;
    const float bv = bias[col];
#pragma unroll
    for (int i = 0; i < 4; ++i) {
      const int mbase = m0 + wm * 64 + i * 16 + quad * 4;
#pragma unroll
      for (int r = 0; r < 4; ++r)
        out[(size_t)(mbase + r) * D_ + col] = acc[i][j][r] + bv;
    }
  }
}

// ---------------------------------------------------------------------------
// R5 attention: uniform-wave decomposition.
// One wave owns one 16-row q-tile over its FULL k-range; the 4 waves of a
// block share the same tile index t but different (b,h) -> identical work,
// zero intra-block idle (R4's 22% occupancy was heavy/light wave pairing).
// Grid (bhg=8, t=64 heavy-first, ch=2) = 1024 blocks x 256 thr.
// Barrier-free, DPP scans, no-max softmax (|s| small; e <= 1).
// ---------------------------------------------------------------------------
__global__ __launch_bounds__(256) void attn_mfma(
    const unsigned short* __restrict__ qkv, const float* __restrict__ gammas,
    unsigned short* __restrict__ Obase)
{
  __shared__ unsigned short Ps[4][16][72];   // per-wave P relayout tile

  const int tid = threadIdx.x;
  const int w = tid >> 6, lane = tid & 63, quad = lane >> 4, l16 = lane & 15;
  const int t  = 63 - blockIdx.y;            // row-tile, heavy first
  const int bh = (blockIdx.x << 2) + w;      // wave-private (b,h)
  const int ch = blockIdx.z;
  const int b = bh >> 3, h = bh & 7;
  const int nc = (t >> 2) + 1;               // number of 64-key chunks
  const int row0 = t << 4;

  const unsigned short* Q  = qkv + (size_t)ch * 3 * SZ_ + (size_t)bh * S_ * DK_;
  const unsigned short* K  = qkv + (size_t)ch * 3 * SZ_ + SZ_ + (size_t)bh * S_ * DK_;
  const unsigned short* Vt = qkv + (size_t)ch * 3 * SZ_ + 2 * SZ_ + (size_t)bh * (size_t)DK_ * S_;
  unsigned short* O = Obase + (size_t)ch * SZ_;

  const float g = gammas[h];
  const float gv = -(fmaxf(g, 0.f) + log1pf(__expf(-fabsf(g))));  // -softplus

  // Q fragments, direct from global (held all kernel)
  const unsigned short* Qrow = Q + (size_t)(row0 + l16) * DK_;
  const bf16x8 qf0 = *(const bf16x8*)(Qrow + quad * 8);
  const bf16x8 qf1 = *(const bf16x8*)(Qrow + 32 + quad * 8);
  const int myrow = row0 + quad * 4;   // + r

  // ===================== pass A: T = sum exp(s) =====================
  float Tacc[4] = {0.f, 0.f, 0.f, 0.f};
  for (int c = 0; c < nc; ++c) {
    f32x4 sa[4];
#pragma unroll
    for (int cb = 0; cb < 4; ++cb) {
      const unsigned short* Kr = K + (size_t)(c * 64 + cb * 16 + l16) * DK_;
      const bf16x8 kf0 = *(const bf16x8*)(Kr + quad * 8);
      const bf16x8 kf1 = *(const bf16x8*)(Kr + 32 + quad * 8);
      f32x4 a = {0.f, 0.f, 0.f, 0.f};
      a = __builtin_amdgcn_mfma_f32_16x16x32_bf16(qf0, kf0, a, 0, 0, 0);
      a = __builtin_amdgcn_mfma_f32_16x16x32_bf16(qf1, kf1, a, 0, 0, 0);
      sa[cb] = a;
    }
    if (c == nc - 1) {
#pragma unroll
      for (int cb = 0; cb < 4; ++cb)
#pragma unroll
        for (int r = 0; r < 4; ++r) {
          float e = __expf(sa[cb][r] * 0.125f);
          if ((c * 64 + cb * 16 + l16) > (myrow + r)) e = 0.f;
          Tacc[r] += e;
        }
    } else {
#pragma unroll
      for (int cb = 0; cb < 4; ++cb)
#pragma unroll
        for (int r = 0; r < 4; ++r)
          Tacc[r] += __expf(sa[cb][r] * 0.125f);
    }
  }
  float invT[4];
#pragma unroll
  for (int r = 0; r < 4; ++r) invT[r] = 1.f / red16(Tacc[r]);

  // ===================== pass B =====================
  float carry[4] = {0.f, 0.f, 0.f, 0.f};
  float l2a[4] = {0.f, 0.f, 0.f, 0.f};
  f32x4 oacc[4];
#pragma unroll
  for (int cb = 0; cb < 4; ++cb) oacc[cb] = (f32x4){0.f, 0.f, 0.f, 0.f};

  for (int c = 0; c < nc; ++c) {
    // V fragments first: consumed at end of iteration -> full-body latency cover
    bf16x8 vf0[4], vf1[4];
#pragma unroll
    for (int cb = 0; cb < 4; ++cb) {
      const unsigned short* Vr = Vt + (size_t)(cb * 16 + l16) * S_ + c * 64;
      vf0[cb] = *(const bf16x8*)(Vr + quad * 8);
      vf1[cb] = *(const bf16x8*)(Vr + 32 + quad * 8);
    }

    f32x4 sa[4];
#pragma unroll
    for (int cb = 0; cb < 4; ++cb) {
      const unsigned short* Kr = K + (size_t)(c * 64 + cb * 16 + l16) * DK_;
      const bf16x8 kf0 = *(const bf16x8*)(Kr + quad * 8);
      const bf16x8 kf1 = *(const bf16x8*)(Kr + 32 + quad * 8);
      f32x4 a = {0.f, 0.f, 0.f, 0.f};
      a = __builtin_amdgcn_mfma_f32_16x16x32_bf16(qf0, kf0, a, 0, 0, 0);
      a = __builtin_amdgcn_mfma_f32_16x16x32_bf16(qf1, kf1, a, 0, 0, 0);
      sa[cb] = a;
    }
#pragma unroll
    for (int cb = 0; cb < 4; ++cb)
#pragma unroll
      for (int r = 0; r < 4; ++r) sa[cb][r] *= 0.125f;
    if (c == nc - 1) {
#pragma unroll
      for (int cb = 0; cb < 4; ++cb)
#pragma unroll
        for (int r = 0; r < 4; ++r)
          if ((c * 64 + cb * 16 + l16) > (myrow + r)) sa[cb][r] = -1e30f;
    }

#pragma unroll
    for (int r = 0; r < 4; ++r) {
      // unnormalized softmax-1 terms + DPP prefix scan per 16-col group
      float v0 = scan16(__expf(sa[0][r]));
      float v1 = scan16(__expf(sa[1][r]));
      float v2 = scan16(__expf(sa[2][r]));
      float v3 = scan16(__expf(sa[3][r]));
      const float tt0 = bcast15(v0), tt1 = bcast15(v1);
      const float tt2 = bcast15(v2), tt3 = bcast15(v3);
      const float base = carry[r];
      const float p01 = tt0 + tt1, p012 = p01 + tt2;
      const float cum0 = (base + v0) * invT[r];
      const float cum1 = (base + tt0 + v1) * invT[r];
      const float cum2 = (base + p01 + v2) * invT[r];
      const float cum3 = (base + p012 + v3) * invT[r];
      carry[r] = base + p012 + tt3;

      // distance decay: e = max(exp(sqrt(clip((1-cum)*pos,0))*gv), 1e-5); e<=1
      const float bpos = (float)(myrow + r) - (float)(c * 64 + l16);
      float st0, st1, st2, st3;
      {
        float dd = sqrtf(fmaxf((1.f - cum0) * bpos, 0.f));
        st0 = sa[0][r] * fmaxf(__expf(dd * gv), 1e-5f);
        dd = sqrtf(fmaxf((1.f - cum1) * (bpos - 16.f), 0.f));
        st1 = sa[1][r] * fmaxf(__expf(dd * gv), 1e-5f);
        dd = sqrtf(fmaxf((1.f - cum2) * (bpos - 32.f), 0.f));
        st2 = sa[2][r] * fmaxf(__expf(dd * gv), 1e-5f);
        dd = sqrtf(fmaxf((1.f - cum3) * (bpos - 48.f), 0.f));
        st3 = sa[3][r] * fmaxf(__expf(dd * gv), 1e-5f);
      }

      // unnormalized softmax-2 weights (lane-partial l2)
      const float w0 = __expf(st0), w1 = __expf(st1);
      const float w2 = __expf(st2), w3 = __expf(st3);
      l2a[r] += (w0 + w1) + (w2 + w3);
      const int prow = quad * 4 + r;
      Ps[w][prow][ 0 + l16] = f2bf(w0);
      Ps[w][prow][16 + l16] = f2bf(w1);
      Ps[w][prow][32 + l16] = f2bf(w2);
      Ps[w][prow][48 + l16] = f2bf(w3);
    }
    asm volatile("s_waitcnt lgkmcnt(0)" ::: "memory");  // wave-private Ps

    const bf16x8 pf0 = *(const bf16x8*)&Ps[w][l16][quad * 8];
    const bf16x8 pf1 = *(const bf16x8*)&Ps[w][l16][32 + quad * 8];
#pragma unroll
    for (int cb = 0; cb < 4; ++cb) {
      oacc[cb] = __builtin_amdgcn_mfma_f32_16x16x32_bf16(pf0, vf0[cb], oacc[cb], 0, 0, 0);
      oacc[cb] = __builtin_amdgcn_mfma_f32_16x16x32_bf16(pf1, vf1[cb], oacc[cb], 0, 0, 0);
    }
  }

  // ---- epilogue ----
#pragma unroll
  for (int r = 0; r < 4; ++r) {
    const float inv = 1.f / red16(l2a[r]);
    const int srow = myrow + r;
    const size_t base = ((size_t)b * S_ + srow) * D_ + h * DK_;
    O[base +  0 + l16] = f2bf(oacc[0][r] * inv);
    O[base + 16 + l16] = f2bf(oacc[1][r] * inv);
    O[base + 32 + l16] = f2bf(oacc[2][r] * inv);
    O[base + 48 + l16] = f2bf(oacc[3][r] * inv);
  }
}

// ---------------------------------------------------------------------------
// Launch (only attn grid changed vs R4).
// ---------------------------------------------------------------------------
extern "C" void kernel_launch(void* const* d_in, const int* in_sizes, int n_in,
                              void* d_out, int out_size, void* d_ws, size_t ws_size,
                              hipStream_t stream) {
  const float* query_mean  = (const float*)d_in[0];
  const float* query_cov   = (const float*)d_in[1];
  const float* key_mean    = (const float*)d_in[2];
  const float* key_cov     = (const float*)d_in[3];
  const float* values_mean = (const float*)d_in[4];
  const float* values_cov  = (const float*)d_in[5];
  const float* Wk_mean = (const float*)d_in[6];
  const float* bk_mean = (const float*)d_in[7];
  const float* Wk_cov  = (const float*)d_in[8];
  const float* bk_cov  = (const float*)d_in[9];
  const float* Wv_mean = (const float*)d_in[10];
  const float* bv_mean = (const float*)d_in[11];
  const float* Wv_cov  = (const float*)d_in[12];
  const float* bv_cov  = (const float*)d_in[13];
  const float* Wo_mean = (const float*)d_in[14];
  const float* bo_mean = (const float*)d_in[15];
  const float* Wo_cov  = (const float*)d_in[16];
  const float* bo_cov  = (const float*)d_in[17];
  const float* gammas  = (const float*)d_in[18];

  unsigned short* qkv  = (unsigned short*)d_ws;
  unsigned short* obuf = qkv + 6 * SZ_;
  unsigned short* Wt4  = (unsigned short*)d_out;       // d_out as scratch
  unsigned short* Wot  = qkv + 2 * SZ_;                // V^T-mean slot, dead after attn
  float* out = (float*)d_out;

  TpArgs t1;
  t1.W[0] = Wk_mean; t1.W[1] = Wv_mean; t1.W[2] = Wk_cov; t1.W[3] = Wv_cov;
  for (int i = 0; i < 4; ++i) t1.out[i] = Wt4 + (size_t)i * WSZ_;
  wtrans<<<dim3(64, 1, 4), 256, 0, stream>>>(t1);

  ProjArgs pa;
  const float* pA[6] = {query_mean, key_mean, values_mean, query_cov, key_cov, values_cov};
  const int   wIdx[6] = {0, 0, 1, 2, 2, 3};
  const float* pb[6] = {bk_mean, bk_mean, bv_mean, bk_cov, bk_cov, bv_cov};
  const int pv[6] = {0, 0, 1, 0, 0, 1};
  for (int i = 0; i < 6; ++i) {
    pa.A[i] = pA[i]; pa.Wt[i] = Wt4 + (size_t)wIdx[i] * WSZ_; pa.bias[i] = pb[i];
    pa.out[i] = qkv + (size_t)i * SZ_; pa.vmode[i] = pv[i];
  }
  proj_mfma<<<dim3(4, 32, 6), 256, 0, stream>>>(pa);

  attn_mfma<<<dim3(8, 64, 2), 256, 0, stream>>>(qkv, gammas, obuf);

  TpArgs t2;
  t2.W[0] = Wo_mean; t2.W[1] = Wo_cov; t2.W[2] = Wo_mean; t2.W[3] = Wo_cov;
  t2.out[0] = Wot; t2.out[1] = Wot + WSZ_; t2.out[2] = Wot; t2.out[3] = Wot + WSZ_;
  wtrans<<<dim3(64, 1, 2), 256, 0, stream>>>(t2);

  OutArgs oa;
  oa.A[0] = obuf;        oa.A[1] = obuf + SZ_;
  oa.Wt[0] = Wot;        oa.Wt[1] = Wot + WSZ_;
  oa.bias[0] = bo_mean;  oa.bias[1] = bo_cov;
  oa.out[0] = out;       oa.out[1] = out + (size_t)MROWS_ * D_;
  out_mfma<<<dim3(4, 32, 2), 256, 0, stream>>>(oa);
}

// Round 6
// 278.230 us; speedup vs baseline: 1.0618x; 1.0618x over previous
//
#include <hip/hip_runtime.h>
#include <hip/hip_bf16.h>
#include <math.h>

constexpr int B_  = 4;
constexpr int S_  = 1024;
constexpr int D_  = 512;
constexpr int H_  = 8;
constexpr int DK_ = 64;
constexpr int MROWS_ = B_ * S_;          // 4096
constexpr size_t SZ_ = (size_t)B_ * H_ * S_ * DK_;  // 2M elems per tensor
constexpr size_t WSZ_ = (size_t)D_ * D_;            // 256K elems per weight

typedef __attribute__((ext_vector_type(8))) short bf16x8;
typedef __attribute__((ext_vector_type(4))) float f32x4;

__device__ __forceinline__ float bf2f(unsigned short u) {
  union { unsigned int u; float f; } v; v.u = (unsigned int)u << 16; return v.f;
}
__device__ __forceinline__ unsigned short f2bf(float f) {
  union { float f; unsigned int u; } v; v.f = f;
  unsigned int r = v.u + 0x7FFFu + ((v.u >> 16) & 1u);   // RNE
  return (unsigned short)(r >> 16);
}

// ---- DPP cross-lane helpers (VALU pipe, no LDS) ----
template <int CTRL>
__device__ __forceinline__ float dpp_mov_f(float x) {
  return __builtin_bit_cast(float,
      __builtin_amdgcn_update_dpp(0, __builtin_bit_cast(int, x), CTRL, 0xF, 0xF, true));
}
__device__ __forceinline__ float scan16(float v) {
  v += dpp_mov_f<0x111>(v);   // row_shr:1
  v += dpp_mov_f<0x112>(v);   // row_shr:2
  v += dpp_mov_f<0x114>(v);   // row_shr:4
  v += dpp_mov_f<0x118>(v);   // row_shr:8
  return v;
}
__device__ __forceinline__ float red16(float v) {
  v += dpp_mov_f<0x128>(v);   // row_ror:8
  v += dpp_mov_f<0x124>(v);   // row_ror:4
  v += dpp_mov_f<0x122>(v);   // row_ror:2
  v += dpp_mov_f<0x121>(v);   // row_ror:1
  return v;
}
// broadcast lane15 of each 16-lane group
__device__ __forceinline__ float bcast15(float v) {
  return __builtin_bit_cast(float,
      __builtin_amdgcn_ds_swizzle(__builtin_bit_cast(int, v), 0x01F0));
}

// ---------------------------------------------------------------------------
// W transpose+convert (unchanged).
// ---------------------------------------------------------------------------
struct TpArgs { const float* W[4]; unsigned short* out[4]; };

__global__ __launch_bounds__(256) void wtrans(TpArgs a) {
  const int z = blockIdx.z;
  const float* __restrict__ W = a.W[z];
  unsigned short* __restrict__ out = a.out[z];
  __shared__ float T[64][65];
  const int tid = threadIdx.x;
  const int tx = blockIdx.x & 7, ty = blockIdx.x >> 3;
  const int k0 = ty * 64, n0 = tx * 64;
#pragma unroll
  for (int i = 0; i < 4; ++i) {
    const int idx = tid + i * 256;
    const int r = idx >> 4, c4 = (idx & 15) * 4;
    const float4 w = *(const float4*)&W[(size_t)(k0 + r) * D_ + n0 + c4];
    T[r][c4 + 0] = w.x; T[r][c4 + 1] = w.y; T[r][c4 + 2] = w.z; T[r][c4 + 3] = w.w;
  }
  __syncthreads();
#pragma unroll
  for (int i = 0; i < 4; ++i) {
    const int idx = tid + i * 256;
    const int n = idx >> 4, kc = (idx & 15) * 4;
    ushort4 pk;
    pk.x = f2bf(T[kc + 0][n]); pk.y = f2bf(T[kc + 1][n]);
    pk.z = f2bf(T[kc + 2][n]); pk.w = f2bf(T[kc + 3][n]);
    *(ushort4*)&out[(size_t)(n0 + n) * D_ + k0 + kc] = pk;
  }
}

// ---------------------------------------------------------------------------
// MFMA projection GEMM (unchanged).
// ---------------------------------------------------------------------------
struct ProjArgs {
  const float* A[6]; const unsigned short* Wt[6]; const float* bias[6];
  unsigned short* out[6]; int vmode[6];
};

__global__ __launch_bounds__(256) void proj_mfma(ProjArgs args) {
  const int z = blockIdx.z;
  const float* __restrict__ A = args.A[z];
  const unsigned short* __restrict__ Wt = args.Wt[z];
  const float* __restrict__ bias = args.bias[z];
  unsigned short* __restrict__ out = args.out[z];
  const int vmode = args.vmode[z];

  __shared__ unsigned short Abuf[128][40];
  __shared__ unsigned short Bbuf[128][40];
  const int tid = threadIdx.x, wv = tid >> 6, lane = tid & 63;
  const int quad = lane >> 4, l16 = lane & 15;
  const int wm = wv >> 1, wn = wv & 1;
  const int n0 = blockIdx.x * 128, m0 = blockIdx.y * 128;

  f32x4 acc[4][4];
#pragma unroll
  for (int i = 0; i < 4; ++i)
#pragma unroll
    for (int j = 0; j < 4; ++j) acc[i][j] = (f32x4){0.f, 0.f, 0.f, 0.f};

  for (int kt = 0; kt < 16; ++kt) {
    const int k0 = kt * 32;
    __syncthreads();
#pragma unroll
    for (int i = 0; i < 4; ++i) {
      const int idx = tid + i * 256;
      const int m = idx >> 3, c = idx & 7;
      const float4 av = *(const float4*)&A[(size_t)(m0 + m) * D_ + k0 + c * 4];
      ushort4 p;
      p.x = f2bf(av.x); p.y = f2bf(av.y); p.z = f2bf(av.z); p.w = f2bf(av.w);
      *(ushort4*)&Abuf[m][c * 4] = p;
    }
#pragma unroll
    for (int i = 0; i < 2; ++i) {
      const int idx = tid + i * 256;
      const int n = idx >> 2, c = idx & 3;
      *(uint4*)&Bbuf[n][c * 8] = *(const uint4*)&Wt[(size_t)(n0 + n) * D_ + k0 + c * 8];
    }
    __syncthreads();

    bf16x8 af[4], bfr[4];
#pragma unroll
    for (int i = 0; i < 4; ++i) af[i] = *(const bf16x8*)&Abuf[wm * 64 + i * 16 + l16][quad * 8];
#pragma unroll
    for (int j = 0; j < 4; ++j) bfr[j] = *(const bf16x8*)&Bbuf[wn * 64 + j * 16 + l16][quad * 8];
#pragma unroll
    for (int i = 0; i < 4; ++i)
#pragma unroll
      for (int j = 0; j < 4; ++j)
        acc[i][j] = __builtin_amdgcn_mfma_f32_16x16x32_bf16(af[i], bfr[j], acc[i][j], 0, 0, 0);
  }

#pragma unroll
  for (int j = 0; j < 4; ++j) {
    const int col = n0 + wn * 64 + j * 16 + l16;
    const float bv = bias[col];
    const int h = col >> 6, dk = col & 63;
#pragma unroll
    for (int i = 0; i < 4; ++i) {
      const int mbase = m0 + wm * 64 + i * 16 + quad * 4;
      const int b = mbase >> 10;
      if (!vmode) {
#pragma unroll
        for (int r = 0; r < 4; ++r) {
          const int s = (mbase + r) & 1023;
          out[(((size_t)b * H_ + h) * S_ + s) * DK_ + dk] = f2bf(acc[i][j][r] + bv);
        }
      } else {
        const int s = mbase & 1023;
        ushort4 pk;
        pk.x = f2bf(acc[i][j][0] + bv); pk.y = f2bf(acc[i][j][1] + bv);
        pk.z = f2bf(acc[i][j][2] + bv); pk.w = f2bf(acc[i][j][3] + bv);
        *(ushort4*)&out[(((size_t)b * H_ + h) * DK_ + dk) * S_ + s] = pk;
      }
    }
  }
}

// ---------------------------------------------------------------------------
// MFMA output GEMM (unchanged).
// ---------------------------------------------------------------------------
struct OutArgs {
  const unsigned short* A[2]; const unsigned short* Wt[2];
  const float* bias[2]; float* out[2];
};

__global__ __launch_bounds__(256) void out_mfma(OutArgs args) {
  const int z = blockIdx.z;
  const unsigned short* __restrict__ A = args.A[z];
  const unsigned short* __restrict__ Wt = args.Wt[z];
  const float* __restrict__ bias = args.bias[z];
  float* __restrict__ out = args.out[z];

  __shared__ unsigned short Abuf[128][40];
  __shared__ unsigned short Bbuf[128][40];
  const int tid = threadIdx.x, wv = tid >> 6, lane = tid & 63;
  const int quad = lane >> 4, l16 = lane & 15;
  const int wm = wv >> 1, wn = wv & 1;
  const int n0 = blockIdx.x * 128, m0 = blockIdx.y * 128;

  f32x4 acc[4][4];
#pragma unroll
  for (int i = 0; i < 4; ++i)
#pragma unroll
    for (int j = 0; j < 4; ++j) acc[i][j] = (f32x4){0.f, 0.f, 0.f, 0.f};

  for (int kt = 0; kt < 16; ++kt) {
    const int k0 = kt * 32;
    __syncthreads();
#pragma unroll
    for (int i = 0; i < 2; ++i) {
      const int idx = tid + i * 256;
      const int m = idx >> 2, c = idx & 3;
      *(uint4*)&Abuf[m][c * 8] = *(const uint4*)&A[(size_t)(m0 + m) * D_ + k0 + c * 8];
    }
#pragma unroll
    for (int i = 0; i < 2; ++i) {
      const int idx = tid + i * 256;
      const int n = idx >> 2, c = idx & 3;
      *(uint4*)&Bbuf[n][c * 8] = *(const uint4*)&Wt[(size_t)(n0 + n) * D_ + k0 + c * 8];
    }
    __syncthreads();

    bf16x8 af[4], bfr[4];
#pragma unroll
    for (int i = 0; i < 4; ++i) af[i] = *(const bf16x8*)&Abuf[wm * 64 + i * 16 + l16][quad * 8];
#pragma unroll
    for (int j = 0; j < 4; ++j) bfr[j] = *(const bf16x8*)&Bbuf[wn * 64 + j * 16 + l16][quad * 8];
#pragma unroll
    for (int i = 0; i < 4; ++i)
#pragma unroll
      for (int j = 0; j < 4; ++j)
        acc[i][j] = __builtin_amdgcn_mfma_f32_16x16x32_bf16(af[i], bfr[j], acc[i][j], 0, 0, 0);
  }

#pragma unroll
  for (int j = 0; j < 4; ++j) {
    const int col = n0 + wn * 64 + j * 16 + l16;
    const float bv = bias[col];
#pragma unroll
    for (int i = 0; i < 4; ++i) {
      const int mbase = m0 + wm * 64 + i * 16 + quad * 4;
#pragma unroll
      for (int r = 0; r < 4; ++r)
        out[(size_t)(mbase + r) * D_ + col] = acc[i][j][r] + bv;
    }
  }
}

// ---------------------------------------------------------------------------
// R6 attention: K-split waves, shared K/V streams, 8192 waves.
// Block = 512 thr (8 waves) = one (b,h,64-row group g):
//   waves 0-3: subtiles 0-3, key chunks [0,h);  waves 4-7: chunks [h,g+1).
// All subtiles of group g need exactly g+1 chunks -> uniform split.
// Pass A computes partial T; one barrier exchanges it: hi-wave's cumsum
// carry-init = lo-wave's unnormalized partial T. Epilogue merges (O,l2)
// pairs via LDS. Grid (bh=32, g=16 heavy-first, ch=2) = 1024 blocks.
// ---------------------------------------------------------------------------
__global__ __launch_bounds__(512) void attn_mfma(
    const unsigned short* __restrict__ qkv, const float* __restrict__ gammas,
    unsigned short* __restrict__ Obase)
{
  __shared__ unsigned short Ps[8][16][72];   // per-wave P relayout tile
  __shared__ float Tpart[2][4][16];          // [half][subtile][row]
  __shared__ float Ex[4][64][21];            // hi->lo partial O(16)+l2(4); pad 21

  const int tid = threadIdx.x;
  const int w = tid >> 6, lane = tid & 63, quad = lane >> 4, l16 = lane & 15;
  const int g  = 15 - blockIdx.y;            // 64-row group, heavy first
  const int bh = blockIdx.x;
  const int ch = blockIdx.z;
  const int sub = w & 3, half = w >> 2;
  const int b = bh >> 3, h = bh & 7;
  const int nc = g + 1;
  const int hsplit = (nc + 1) >> 1;          // lo:[0,hsplit) hi:[hsplit,nc)
  const int c_begin = half ? hsplit : 0;
  const int c_end   = half ? nc : hsplit;
  const int row0 = g * 64 + sub * 16;

  const unsigned short* Q  = qkv + (size_t)ch * 3 * SZ_ + (size_t)bh * S_ * DK_;
  const unsigned short* K  = qkv + (size_t)ch * 3 * SZ_ + SZ_ + (size_t)bh * S_ * DK_;
  const unsigned short* Vt = qkv + (size_t)ch * 3 * SZ_ + 2 * SZ_ + (size_t)bh * (size_t)DK_ * S_;
  unsigned short* O = Obase + (size_t)ch * SZ_;

  const float g0 = gammas[h];
  const float gv = -(fmaxf(g0, 0.f) + log1pf(__expf(-fabsf(g0))));  // -softplus

  const unsigned short* Qrow = Q + (size_t)(row0 + l16) * DK_;
  const bf16x8 qf0 = *(const bf16x8*)(Qrow + quad * 8);
  const bf16x8 qf1 = *(const bf16x8*)(Qrow + 32 + quad * 8);
  const int myrow = row0 + quad * 4;   // + r

  // ===== pass A: partial T over [c_begin, c_end) =====
  float Tacc[4] = {0.f, 0.f, 0.f, 0.f};
  for (int c = c_begin; c < c_end; ++c) {
    f32x4 sa[4];
#pragma unroll
    for (int cb = 0; cb < 4; ++cb) {
      const unsigned short* Kr = K + (size_t)(c * 64 + cb * 16 + l16) * DK_;
      const bf16x8 kf0 = *(const bf16x8*)(Kr + quad * 8);
      const bf16x8 kf1 = *(const bf16x8*)(Kr + 32 + quad * 8);
      f32x4 a = {0.f, 0.f, 0.f, 0.f};
      a = __builtin_amdgcn_mfma_f32_16x16x32_bf16(qf0, kf0, a, 0, 0, 0);
      a = __builtin_amdgcn_mfma_f32_16x16x32_bf16(qf1, kf1, a, 0, 0, 0);
      sa[cb] = a;
    }
    if (c == g) {
#pragma unroll
      for (int cb = 0; cb < 4; ++cb)
#pragma unroll
        for (int r = 0; r < 4; ++r) {
          float e = __expf(sa[cb][r] * 0.125f);
          if ((c * 64 + cb * 16 + l16) > (myrow + r)) e = 0.f;
          Tacc[r] += e;
        }
    } else {
#pragma unroll
      for (int cb = 0; cb < 4; ++cb)
#pragma unroll
        for (int r = 0; r < 4; ++r)
          Tacc[r] += __expf(sa[cb][r] * 0.125f);
    }
  }
#pragma unroll
  for (int r = 0; r < 4; ++r) Tacc[r] = red16(Tacc[r]);
  if (l16 == 0) {
#pragma unroll
    for (int r = 0; r < 4; ++r) Tpart[half][sub][quad * 4 + r] = Tacc[r];
  }
  __syncthreads();

  float invT[4], carry[4];
#pragma unroll
  for (int r = 0; r < 4; ++r) {
    const float tlo = Tpart[0][sub][quad * 4 + r];
    const float thi = Tpart[1][sub][quad * 4 + r];
    invT[r] = 1.f / (tlo + thi);
    carry[r] = half ? tlo : 0.f;
  }

  // ===== pass B over [c_begin, c_end) =====
  float l2a[4] = {0.f, 0.f, 0.f, 0.f};
  f32x4 oacc[4];
#pragma unroll
  for (int cb = 0; cb < 4; ++cb) oacc[cb] = (f32x4){0.f, 0.f, 0.f, 0.f};

  for (int c = c_begin; c < c_end; ++c) {
    bf16x8 vf0[4], vf1[4];
#pragma unroll
    for (int cb = 0; cb < 4; ++cb) {
      const unsigned short* Vr = Vt + (size_t)(cb * 16 + l16) * S_ + c * 64;
      vf0[cb] = *(const bf16x8*)(Vr + quad * 8);
      vf1[cb] = *(const bf16x8*)(Vr + 32 + quad * 8);
    }

    f32x4 sa[4];
#pragma unroll
    for (int cb = 0; cb < 4; ++cb) {
      const unsigned short* Kr = K + (size_t)(c * 64 + cb * 16 + l16) * DK_;
      const bf16x8 kf0 = *(const bf16x8*)(Kr + quad * 8);
      const bf16x8 kf1 = *(const bf16x8*)(Kr + 32 + quad * 8);
      f32x4 a = {0.f, 0.f, 0.f, 0.f};
      a = __builtin_amdgcn_mfma_f32_16x16x32_bf16(qf0, kf0, a, 0, 0, 0);
      a = __builtin_amdgcn_mfma_f32_16x16x32_bf16(qf1, kf1, a, 0, 0, 0);
      sa[cb] = a;
    }
#pragma unroll
    for (int cb = 0; cb < 4; ++cb)
#pragma unroll
      for (int r = 0; r < 4; ++r) sa[cb][r] *= 0.125f;
    if (c == g) {
#pragma unroll
      for (int cb = 0; cb < 4; ++cb)
#pragma unroll
        for (int r = 0; r < 4; ++r)
          if ((c * 64 + cb * 16 + l16) > (myrow + r)) sa[cb][r] = -1e30f;
    }

#pragma unroll
    for (int r = 0; r < 4; ++r) {
      float v0 = scan16(__expf(sa[0][r]));
      float v1 = scan16(__expf(sa[1][r]));
      float v2 = scan16(__expf(sa[2][r]));
      float v3 = scan16(__expf(sa[3][r]));
      const float tt0 = bcast15(v0), tt1 = bcast15(v1);
      const float tt2 = bcast15(v2), tt3 = bcast15(v3);
      const float base = carry[r];
      const float p01 = tt0 + tt1, p012 = p01 + tt2;
      const float cum0 = (base + v0) * invT[r];
      const float cum1 = (base + tt0 + v1) * invT[r];
      const float cum2 = (base + p01 + v2) * invT[r];
      const float cum3 = (base + p012 + v3) * invT[r];
      carry[r] = base + p012 + tt3;

      const float bpos = (float)(myrow + r) - (float)(c * 64 + l16);
      float st0, st1, st2, st3;
      {
        float dd = sqrtf(fmaxf((1.f - cum0) * bpos, 0.f));
        st0 = sa[0][r] * fmaxf(__expf(dd * gv), 1e-5f);
        dd = sqrtf(fmaxf((1.f - cum1) * (bpos - 16.f), 0.f));
        st1 = sa[1][r] * fmaxf(__expf(dd * gv), 1e-5f);
        dd = sqrtf(fmaxf((1.f - cum2) * (bpos - 32.f), 0.f));
        st2 = sa[2][r] * fmaxf(__expf(dd * gv), 1e-5f);
        dd = sqrtf(fmaxf((1.f - cum3) * (bpos - 48.f), 0.f));
        st3 = sa[3][r] * fmaxf(__expf(dd * gv), 1e-5f);
      }

      const float w0 = __expf(st0), w1 = __expf(st1);
      const float w2 = __expf(st2), w3 = __expf(st3);
      l2a[r] += (w0 + w1) + (w2 + w3);
      const int prow = quad * 4 + r;
      Ps[w][prow][ 0 + l16] = f2bf(w0);
      Ps[w][prow][16 + l16] = f2bf(w1);
      Ps[w][prow][32 + l16] = f2bf(w2);
      Ps[w][prow][48 + l16] = f2bf(w3);
    }
    asm volatile("s_waitcnt lgkmcnt(0)" ::: "memory");  // wave-private Ps

    const bf16x8 pf0 = *(const bf16x8*)&Ps[w][l16][quad * 8];
    const bf16x8 pf1 = *(const bf16x8*)&Ps[w][l16][32 + quad * 8];
#pragma unroll
    for (int cb = 0; cb < 4; ++cb) {
      oacc[cb] = __builtin_amdgcn_mfma_f32_16x16x32_bf16(pf0, vf0[cb], oacc[cb], 0, 0, 0);
      oacc[cb] = __builtin_amdgcn_mfma_f32_16x16x32_bf16(pf1, vf1[cb], oacc[cb], 0, 0, 0);
    }
  }

  // ===== epilogue: merge halves, normalize, store =====
  if (half) {
#pragma unroll
    for (int cb = 0; cb < 4; ++cb)
#pragma unroll
      for (int r = 0; r < 4; ++r) Ex[sub][lane][cb * 4 + r] = oacc[cb][r];
#pragma unroll
    for (int r = 0; r < 4; ++r) Ex[sub][lane][16 + r] = l2a[r];
  }
  __syncthreads();
  if (!half) {
#pragma unroll
    for (int cb = 0; cb < 4; ++cb)
#pragma unroll
      for (int r = 0; r < 4; ++r) oacc[cb][r] += Ex[sub][lane][cb * 4 + r];
#pragma unroll
    for (int r = 0; r < 4; ++r) l2a[r] += Ex[sub][lane][16 + r];
#pragma unroll
    for (int r = 0; r < 4; ++r) {
      const float inv = 1.f / red16(l2a[r]);
      const int srow = myrow + r;
      const size_t base = ((size_t)b * S_ + srow) * D_ + h * DK_;
      O[base +  0 + l16] = f2bf(oacc[0][r] * inv);
      O[base + 16 + l16] = f2bf(oacc[1][r] * inv);
      O[base + 32 + l16] = f2bf(oacc[2][r] * inv);
      O[base + 48 + l16] = f2bf(oacc[3][r] * inv);
    }
  }
}

// ---------------------------------------------------------------------------
// Launch (only attn grid/block changed vs R5).
// ---------------------------------------------------------------------------
extern "C" void kernel_launch(void* const* d_in, const int* in_sizes, int n_in,
                              void* d_out, int out_size, void* d_ws, size_t ws_size,
                              hipStream_t stream) {
  const float* query_mean  = (const float*)d_in[0];
  const float* query_cov   = (const float*)d_in[1];
  const float* key_mean    = (const float*)d_in[2];
  const float* key_cov     = (const float*)d_in[3];
  const float* values_mean = (const float*)d_in[4];
  const float* values_cov  = (const float*)d_in[5];
  const float* Wk_mean = (const float*)d_in[6];
  const float* bk_mean = (const float*)d_in[7];
  const float* Wk_cov  = (const float*)d_in[8];
  const float* bk_cov  = (const float*)d_in[9];
  const float* Wv_mean = (const float*)d_in[10];
  const float* bv_mean = (const float*)d_in[11];
  const float* Wv_cov  = (const float*)d_in[12];
  const float* bv_cov  = (const float*)d_in[13];
  const float* Wo_mean = (const float*)d_in[14];
  const float* bo_mean = (const float*)d_in[15];
  const float* Wo_cov  = (const float*)d_in[16];
  const float* bo_cov  = (const float*)d_in[17];
  const float* gammas  = (const float*)d_in[18];

  unsigned short* qkv  = (unsigned short*)d_ws;
  unsigned short* obuf = qkv + 6 * SZ_;
  unsigned short* Wt4  = (unsigned short*)d_out;       // d_out as scratch
  unsigned short* Wot  = qkv + 2 * SZ_;                // V^T-mean slot, dead after attn
  float* out = (float*)d_out;

  TpArgs t1;
  t1.W[0] = Wk_mean; t1.W[1] = Wv_mean; t1.W[2] = Wk_cov; t1.W[3] = Wv_cov;
  for (int i = 0; i < 4; ++i) t1.out[i] = Wt4 + (size_t)i * WSZ_;
  wtrans<<<dim3(64, 1, 4), 256, 0, stream>>>(t1);

  ProjArgs pa;
  const float* pA[6] = {query_mean, key_mean, values_mean, query_cov, key_cov, values_cov};
  const int   wIdx[6] = {0, 0, 1, 2, 2, 3};
  const float* pb[6] = {bk_mean, bk_mean, bv_mean, bk_cov, bk_cov, bv_cov};
  const int pv[6] = {0, 0, 1, 0, 0, 1};
  for (int i = 0; i < 6; ++i) {
    pa.A[i] = pA[i]; pa.Wt[i] = Wt4 + (size_t)wIdx[i] * WSZ_; pa.bias[i] = pb[i];
    pa.out[i] = qkv + (size_t)i * SZ_; pa.vmode[i] = pv[i];
  }
  proj_mfma<<<dim3(4, 32, 6), 256, 0, stream>>>(pa);

  attn_mfma<<<dim3(32, 16, 2), 512, 0, stream>>>(qkv, gammas, obuf);

  TpArgs t2;
  t2.W[0] = Wo_mean; t2.W[1] = Wo_cov; t2.W[2] = Wo_mean; t2.W[3] = Wo_cov;
  t2.out[0] = Wot; t2.out[1] = Wot + WSZ_; t2.out[2] = Wot; t2.out[3] = Wot + WSZ_;
  wtrans<<<dim3(64, 1, 2), 256, 0, stream>>>(t2);

  OutArgs oa;
  oa.A[0] = obuf;        oa.A[1] = obuf + SZ_;
  oa.Wt[0] = Wot;        oa.Wt[1] = Wot + WSZ_;
  oa.bias[0] = bo_mean;  oa.bias[1] = bo_cov;
  oa.out[0] = out;       oa.out[1] = out + (size_t)MROWS_ * D_;
  out_mfma<<<dim3(4, 32, 2), 256, 0, stream>>>(oa);
}